// Round 4
// baseline (640.780 us; speedup 1.0000x reference)
//
#include <hip/hip_runtime.h>
#include <hip/hip_bf16.h>

#define HH 1024
#define AA 512
#define BB 32
#define SS 1024
#define TN 1024
#define M_ENC (SS*BB)
#define M_TOT ((SS+TN)*BB)
#define NCH 8

typedef __attribute__((ext_vector_type(8))) short short8;
typedef __attribute__((ext_vector_type(4))) float f4;

union bfu { __hip_bfloat16 h; unsigned short u; };
__device__ __forceinline__ unsigned short f2b(float x) {
  bfu t; t.h = __float2bfloat16(x); return t.u;
}
__device__ __forceinline__ float tanh_fast(float x) {
  float e = __expf(2.f * x);
  return 1.f - 2.f / (e + 1.f);
}

// ---- one-time W -> bf16 fragment-order repack ------------------------------
// Wc layout: frag id t = ((kb*32 + rg)*64 + lane), 8 bf16 per frag.
// fragment holds W[rg*16 + (lane&15)][kb*32 + (lane>>4)*8 + j]
__global__ void wprep(const float* __restrict__ W, unsigned short* __restrict__ Wc) {
  const int t = blockIdx.x * 256 + threadIdx.x;     // 0..65535
  const int lane = t & 63;
  const int rg = (t >> 6) & 31;
  const int kb = t >> 11;
  const int row = rg * 16 + (lane & 15);
  const int k = kb * 32 + ((lane >> 4) << 3);
  const float* src = W + (size_t)row * HH + k;
  f4 v0 = *(const f4*)(src);
  f4 v1 = *(const f4*)(src + 4);
  short8 o;
  o[0] = f2b(v0[0]); o[1] = f2b(v0[1]); o[2] = f2b(v0[2]); o[3] = f2b(v0[3]);
  o[4] = f2b(v1[0]); o[5] = f2b(v1[1]); o[6] = f2b(v1[2]); o[7] = f2b(v1[3]);
  *(short8*)(Wc + (size_t)t * 8) = o;
}

// ---- big fused GEMM: e1[row] = sum_a V[a]*tanh( X[row,:] . W[a,:] ) --------
// BM=256 rows/block, grid=256 (1 block/CU). LDS double-buffer staged with
// global_load_lds: A fp32 (XOR-swizzled via pre-swizzled global source),
// B bf16 fragment-ordered (linear). 8 waves = 2 row-groups x 4 col-groups,
// each wave 128x128 -> acc[8][8] f4.
__global__ __launch_bounds__(512, 2)
void e1_gemm(const float* __restrict__ enc, const float* __restrict__ h0,
             const unsigned short* __restrict__ W1c, const unsigned short* __restrict__ W5c,
             const float* __restrict__ W4, const float* __restrict__ W8,
             float* __restrict__ e1) {
  const int wg   = blockIdx.x;        // 256 blocks, 256 rows each
  const int tid  = threadIdx.x;       // 512
  const int lane = tid & 63;
  const int wave = tid >> 6;          // 0..7
  const int rowg = wave >> 2;         // 0..1  (128-row group)
  const int colg = wave & 3;          // 0..3  (128-col group)
  const int l15  = lane & 15;
  const int lg   = lane >> 4;         // 0..3

  const bool is_enc = (wg * 256) < M_ENC;
  const float* __restrict__ Xg = is_enc ? enc : h0;
  const unsigned short* __restrict__ Wc = is_enc ? W1c : W5c;
  const float* __restrict__ Vg = is_enc ? W4 : W8;
  const int row0 = is_enc ? wg * 256 : wg * 256 - M_ENC;

  // LDS: [A0 32K][B0 32K][A1 32K][B1 32K][lred 4K] = 132 KB
  __shared__ char lds_raw[4 * 32768 + 4096];
  float* lred = (float*)(lds_raw + 4 * 32768);   // [4][256]

  float vvv[8];
#pragma unroll
  for (int cf = 0; cf < 8; ++cf) vvv[cf] = Vg[colg * 128 + cf * 16 + l15];

  f4 acc[8][8];
#pragma unroll
  for (int i = 0; i < 8; ++i)
#pragma unroll
    for (int j = 0; j < 8; ++j) acc[i][j] = (f4){0.f, 0.f, 0.f, 0.f};

  // stage one K-step (32 k) into buffer `buf`
#define STAGE(buf, kb_) do {                                                  \
    const int kbase_ = (kb_) * 32;                                            \
    _Pragma("unroll")                                                         \
    for (int r_ = 0; r_ < 4; ++r_) {                                          \
      const int idx_ = r_ * 512 + tid;                                        \
      const int arow_ = idx_ >> 3;                                            \
      const int sl_ = idx_ & 7;                                               \
      const int sg_ = sl_ ^ (arow_ & 7);                                      \
      const float* gA_ = Xg + (size_t)(row0 + arow_) * HH + kbase_ + sg_ * 4; \
      char* lA_ = lds_raw + (buf) * 65536 + idx_ * 16;                        \
      __builtin_amdgcn_global_load_lds(                                       \
          (const __attribute__((address_space(1))) void*)gA_,                 \
          (__attribute__((address_space(3))) void*)lA_, 16, 0, 0);            \
      const char* gB_ = (const char*)Wc + (size_t)(kb_) * 32768 + idx_ * 16;  \
      char* lB_ = lds_raw + (buf) * 65536 + 32768 + idx_ * 16;                \
      __builtin_amdgcn_global_load_lds(                                       \
          (const __attribute__((address_space(1))) void*)gB_,                 \
          (__attribute__((address_space(3))) void*)lB_, 16, 0, 0);            \
    }                                                                         \
  } while (0)

  STAGE(0, 0);
  __syncthreads();

  int cur = 0;
#pragma unroll 1
  for (int kb = 0; kb < 32; ++kb) {
    if (kb < 31) STAGE(cur ^ 1, kb + 1);

    const char* Ab = lds_raw + cur * 65536;
    const char* Bb = Ab + 32768;

    short8 bfr[8];
#pragma unroll
    for (int cf = 0; cf < 8; ++cf)
      bfr[cf] = *(const short8*)(Bb + (((colg * 8 + cf) * 64 + lane) * 16));

#pragma unroll
    for (int rt = 0; rt < 8; ++rt) {
      const int row = rowg * 128 + rt * 16 + l15;
      const int x = row & 7;
      f4 a0 = *(const f4*)(Ab + row * 128 + (((lg * 2)     ^ x) * 16));
      f4 a1 = *(const f4*)(Ab + row * 128 + (((lg * 2 + 1) ^ x) * 16));
      short8 af;
      af[0] = f2b(a0[0]); af[1] = f2b(a0[1]); af[2] = f2b(a0[2]); af[3] = f2b(a0[3]);
      af[4] = f2b(a1[0]); af[5] = f2b(a1[1]); af[6] = f2b(a1[2]); af[7] = f2b(a1[3]);
#pragma unroll
      for (int cf = 0; cf < 8; ++cf)
        acc[rt][cf] = __builtin_amdgcn_mfma_f32_16x16x32_bf16(af, bfr[cf], acc[rt][cf], 0, 0, 0);
    }
    __syncthreads();
    cur ^= 1;
  }
#undef STAGE

  // epilogue: tanh, weight by V, reduce 16 lanes (cols), then across col-groups
#pragma unroll
  for (int rt = 0; rt < 8; ++rt) {
    float ps[4] = {0.f, 0.f, 0.f, 0.f};
#pragma unroll
    for (int cf = 0; cf < 8; ++cf) {
      const float w = vvv[cf];
#pragma unroll
      for (int r = 0; r < 4; ++r) ps[r] += w * tanh_fast(acc[rt][cf][r]);
    }
#pragma unroll
    for (int r = 0; r < 4; ++r) {
#pragma unroll
      for (int off = 1; off < 16; off <<= 1) ps[r] += __shfl_xor(ps[r], off);
    }
    if (l15 == 0) {
#pragma unroll
      for (int r = 0; r < 4; ++r)
        lred[colg * 256 + rowg * 128 + rt * 16 + lg * 4 + r] = ps[r];
    }
  }
  __syncthreads();
  if (tid < 256) {
    float s = lred[tid] + lred[256 + tid] + lred[512 + tid] + lred[768 + tid];
    e1[(size_t)wg * 256 + tid] = s;
  }
}

// ---------------- exi full logits: exf[b][s] = e1[s*B+b] + sum_a W4[2A+a]*tanh(ax[b,s]*W3[a]) ----
__global__ void exf_kernel(const float* __restrict__ e1, const float* __restrict__ ax,
                           const float* __restrict__ W3, const float* __restrict__ W4,
                           float* __restrict__ exf) {
  __shared__ float w3s[AA], w4r[AA];
  const int tid = threadIdx.x;  // 256
  for (int i = tid; i < AA; i += 256) { w3s[i] = W3[i]; w4r[i] = W4[2 * AA + i]; }
  __syncthreads();
  const int b = blockIdx.x >> 2;
  const int s = (blockIdx.x & 3) * 256 + tid;
  const float x = ax[b * SS + s];
  float er = 0.f;
#pragma unroll 8
  for (int a = 0; a < AA; ++a) er += w4r[a] * tanh_fast(x * w3s[a]);
  exf[b * SS + s] = e1[s * BB + b] + er;
}

// ---------------- softmax over s (contiguous rows) + ax_new output ----------------
__global__ void softmax_bs(const float* __restrict__ ein, const float* __restrict__ ax,
                           float* __restrict__ wout, float* __restrict__ axnew) {
  const int b = blockIdx.x, tid = threadIdx.x;  // 256 threads, 1024 elems
  __shared__ float red[256];
  float loc[4];
  float m = -1e30f;
#pragma unroll
  for (int i = 0; i < 4; ++i) { loc[i] = ein[b * SS + i * 256 + tid]; m = fmaxf(m, loc[i]); }
  red[tid] = m; __syncthreads();
  for (int off = 128; off > 0; off >>= 1) {
    if (tid < off) red[tid] = fmaxf(red[tid], red[tid + off]);
    __syncthreads();
  }
  m = red[0]; __syncthreads();
  float sum = 0.f;
#pragma unroll
  for (int i = 0; i < 4; ++i) { loc[i] = __expf(loc[i] - m); sum += loc[i]; }
  red[tid] = sum; __syncthreads();
  for (int off = 128; off > 0; off >>= 1) {
    if (tid < off) red[tid] += red[tid + off];
    __syncthreads();
  }
  const float inv = 1.f / red[0];
#pragma unroll
  for (int i = 0; i < 4; ++i) {
    const int s = i * 256 + tid;
    const float a_ = loc[i] * inv;
    wout[b * SS + s] = a_;
    axnew[b * SS + s] = ax[b * SS + s] + a_;
  }
}

// ---------------- softmax over t, input layout [t][b] strided ----------------
__global__ void softmax_tb(const float* __restrict__ ein, float* __restrict__ wout) {
  const int b = blockIdx.x, tid = threadIdx.x;
  __shared__ float red[256];
  float loc[4];
  float m = -1e30f;
#pragma unroll
  for (int i = 0; i < 4; ++i) { loc[i] = ein[(i * 256 + tid) * BB + b]; m = fmaxf(m, loc[i]); }
  red[tid] = m; __syncthreads();
  for (int off = 128; off > 0; off >>= 1) {
    if (tid < off) red[tid] = fmaxf(red[tid], red[tid + off]);
    __syncthreads();
  }
  m = red[0]; __syncthreads();
  float sum = 0.f;
#pragma unroll
  for (int i = 0; i < 4; ++i) { loc[i] = __expf(loc[i] - m); sum += loc[i]; }
  red[tid] = sum; __syncthreads();
  for (int off = 128; off > 0; off >>= 1) {
    if (tid < off) red[tid] += red[tid + off];
    __syncthreads();
  }
  const float inv = 1.f / red[0];
#pragma unroll
  for (int i = 0; i < 4; ++i) wout[b * TN + (i * 256 + tid)] = loc[i] * inv;
}

// ---------------- chunked weighted sum: part[b][ch][h] = sum_{s in ch} w[b,s]*X[s,b,h] ------------
__global__ void wpart(const float* __restrict__ X, const float* __restrict__ w,
                      float* __restrict__ part) {
  const int b = blockIdx.x / NCH, ch = blockIdx.x % NCH;
  const int tid = threadIdx.x;  // 256, each handles 4 h
  __shared__ float ws[SS / NCH];
  if (tid < SS / NCH) ws[tid] = w[b * SS + ch * (SS / NCH) + tid];
  __syncthreads();
  f4 acc = (f4){0.f, 0.f, 0.f, 0.f};
  const float* base = X + ((size_t)(ch * (SS / NCH)) * BB + b) * HH + tid * 4;
  for (int i = 0; i < SS / NCH; ++i) {
    f4 x = *(const f4*)(base + (size_t)i * BB * HH);
    acc += ws[i] * x;
  }
  *(f4*)&part[((size_t)(b * NCH + ch)) * HH + tid * 4] = acc;
}

__global__ void wreduce(const float* __restrict__ part, float* __restrict__ out) {
  const int idx = blockIdx.x * 256 + threadIdx.x;  // over B*H
  const int b = idx / HH, h = idx % HH;
  float s = 0.f;
#pragma unroll
  for (int ch = 0; ch < NCH; ++ch) s += part[((size_t)(b * NCH + ch)) * HH + h];
  out[idx] = s;
}

// ---------------- zi[b] = sigmoid( cxi[b,:].W11[0:H] + cti[b,:].W11[H:2H] ) ----------------
__global__ void zi_kernel(const float* __restrict__ cxi, const float* __restrict__ cti,
                          const float* __restrict__ W11, float* __restrict__ zi) {
  const int b = blockIdx.x, tid = threadIdx.x;  // 256
  float s = 0.f;
  for (int i = tid; i < HH; i += 256) s += cxi[b * HH + i] * W11[i] + cti[b * HH + i] * W11[HH + i];
  __shared__ float red[4];
  for (int off = 32; off > 0; off >>= 1) s += __shfl_down(s, off);
  if ((tid & 63) == 0) red[tid >> 6] = s;
  __syncthreads();
  if (tid == 0) {
    float t = red[0] + red[1] + red[2] + red[3];
    zi[b] = 1.f / (1.f + __expf(-t));
  }
}

// ---------------- ci[b,h] = z*tanh(cxi.W9[h,:]) + (1-z)*tanh(cti.W10[h,:]) ----------------
__global__ void ci_kernel(const float* __restrict__ cxi, const float* __restrict__ cti,
                          const float* __restrict__ W9, const float* __restrict__ W10,
                          const float* __restrict__ zi, float* __restrict__ out_ci) {
  const int b = blockIdx.x >> 2, hb = blockIdx.x & 3, tid = threadIdx.x;
  const int h = hb * 256 + tid;
  __shared__ float cx[HH], ct[HH];
  for (int i = tid; i < HH; i += 256) { cx[i] = cxi[b * HH + i]; ct[i] = cti[b * HH + i]; }
  __syncthreads();
  const float* __restrict__ w9r  = W9  + (size_t)h * HH;
  const float* __restrict__ w10r = W10 + (size_t)h * HH;
  float gx = 0.f, gt = 0.f;
  for (int k = 0; k < HH; k += 4) {
    f4 a = *(const f4*)(w9r + k);
    f4 c = *(const f4*)(w10r + k);
    gx += cx[k] * a[0] + cx[k + 1] * a[1] + cx[k + 2] * a[2] + cx[k + 3] * a[3];
    gt += ct[k] * c[0] + ct[k + 1] * c[1] + ct[k + 2] * c[2] + ct[k + 3] * c[3];
  }
  const float z = zi[b];
  out_ci[b * HH + h] = z * tanhf(gx) + (1.f - z) * tanhf(gt);
}

extern "C" void kernel_launch(void* const* d_in, const int* in_sizes, int n_in,
                              void* d_out, int out_size, void* d_ws, size_t ws_size,
                              hipStream_t stream) {
  const float* enc = (const float*)d_in[1];
  const float* h0  = (const float*)d_in[2];
  const float* ax  = (const float*)d_in[3];
  const float* W1  = (const float*)d_in[4];
  const float* W3  = (const float*)d_in[6];
  const float* W4  = (const float*)d_in[7];
  const float* W5  = (const float*)d_in[8];
  const float* W8  = (const float*)d_in[11];
  const float* W9  = (const float*)d_in[12];
  const float* W10 = (const float*)d_in[13];
  const float* W11 = (const float*)d_in[14];
  float* out = (float*)d_out;  // [0:B*H) ci, [B*H : 2*B*H) ax_new

  // Workspace layout (floats). W1c/W5c each 512*1024 bf16 = 262144 floats (1MB).
  // partx/partt ALIAS the Wc regions: Wc dead after e1_gemm; wprep recreates
  // Wc at the start of every call (deterministic across graph replays).
  float* w = (float*)d_ws;
  unsigned short* W1c = (unsigned short*)w;            // floats [0, 262144)
  unsigned short* W5c = (unsigned short*)(w + 262144); // floats [262144, 524288)
  float* partx = w;                  // aliases W1c
  float* partt = w + 262144;         // aliases W5c
  float* e1    = w + 524288;         // 65536
  float* exf   = w + 589824;         // 32768
  float* axi   = w + 622592;         // 32768
  float* ati   = w + 655360;         // 32768
  float* cxi   = w + 688128;         // 32768
  float* cti   = w + 720896;         // 32768
  float* zi    = w + 753664;         // 64    (end: ~3.01 MB)

  wprep<<<256, 256, 0, stream>>>(W1, W1c);
  wprep<<<256, 256, 0, stream>>>(W5, W5c);
  e1_gemm<<<M_TOT / 256, 512, 0, stream>>>(enc, h0, W1c, W5c, W4, W8, e1);
  exf_kernel<<<BB * 4, 256, 0, stream>>>(e1, ax, W3, W4, exf);
  softmax_bs<<<BB, 256, 0, stream>>>(exf, ax, axi, out + BB * HH);
  softmax_tb<<<BB, 256, 0, stream>>>(e1 + M_ENC, ati);
  wpart<<<BB * NCH, 256, 0, stream>>>(enc, axi, partx);
  wpart<<<BB * NCH, 256, 0, stream>>>(h0, ati, partt);
  wreduce<<<BB * HH / 256, 256, 0, stream>>>(partx, cxi);
  wreduce<<<BB * HH / 256, 256, 0, stream>>>(partt, cti);
  zi_kernel<<<BB, 256, 0, stream>>>(cxi, cti, W11, zi);
  ci_kernel<<<BB * 4, 256, 0, stream>>>(cxi, cti, W9, W10, zi, out);
}

// Round 5
// 256.400 us; speedup vs baseline: 2.4991x; 2.4991x over previous
//
#include <hip/hip_runtime.h>
#include <hip/hip_bf16.h>

#define HH 1024
#define AA 512
#define BB 32
#define SS 1024
#define TN 1024
#define M_ENC (SS*BB)
#define M_TOT ((SS+TN)*BB)
#define NCH 8

typedef __attribute__((ext_vector_type(8))) short short8;
typedef __attribute__((ext_vector_type(4))) float f4;

union bfu { __hip_bfloat16 h; unsigned short u; };
__device__ __forceinline__ unsigned short f2b(float x) {
  bfu t; t.h = __float2bfloat16(x); return t.u;
}
__device__ __forceinline__ float tanh_fast(float x) {
  float e = __expf(2.f * x);
  return 1.f - 2.f / (e + 1.f);
}

// ---- one-time W -> bf16 fragment-order repack ------------------------------
// Wc layout: frag id t = ((kb*32 + rg)*64 + lane), 8 bf16 per frag.
// fragment holds W[rg*16 + (lane&15)][kb*32 + (lane>>4)*8 + j]
__global__ void wprep(const float* __restrict__ W, unsigned short* __restrict__ Wc) {
  const int t = blockIdx.x * 256 + threadIdx.x;     // 0..65535
  const int lane = t & 63;
  const int rg = (t >> 6) & 31;
  const int kb = t >> 11;
  const int row = rg * 16 + (lane & 15);
  const int k = kb * 32 + ((lane >> 4) << 3);
  const float* src = W + (size_t)row * HH + k;
  f4 v0 = *(const f4*)(src);
  f4 v1 = *(const f4*)(src + 4);
  short8 o;
  o[0] = f2b(v0[0]); o[1] = f2b(v0[1]); o[2] = f2b(v0[2]); o[3] = f2b(v0[3]);
  o[4] = f2b(v1[0]); o[5] = f2b(v1[1]); o[6] = f2b(v1[2]); o[7] = f2b(v1[3]);
  *(short8*)(Wc + (size_t)t * 8) = o;
}

// ---- big fused GEMM: e1[row] = sum_a V[a]*tanh( X[row,:] . W[a,:] ) --------
// BM=128 rows/block, 1024 threads = 16 waves as 2(row)x8(col); wave tile 64x64
// -> acc[4][4] = 64 VGPR (no spill at the 128-VGPR budget of (1024,4)).
// LDS double-buffer staged with global_load_lds: A fp32 XOR-swizzled via
// pre-swizzled global source (rule #21: inverse-swz source + swz read),
// B bf16 fragment-ordered (linear). 96KB+4KB LDS, 1 block/CU, 4 waves/SIMD.
__global__ __launch_bounds__(1024, 4)
void e1_gemm(const float* __restrict__ enc, const float* __restrict__ h0,
             const unsigned short* __restrict__ W1c, const unsigned short* __restrict__ W5c,
             const float* __restrict__ W4, const float* __restrict__ W8,
             float* __restrict__ e1) {
  const int wg   = blockIdx.x;        // 512 blocks, 128 rows each
  const int tid  = threadIdx.x;       // 1024
  const int lane = tid & 63;
  const int wave = tid >> 6;          // 0..15
  const int rowg = wave >> 3;         // 0..1  (64-row group)
  const int colg = wave & 7;          // 0..7  (64-col group)
  const int l15  = lane & 15;
  const int lg   = lane >> 4;         // 0..3

  const bool is_enc = (wg * 128) < M_ENC;
  const float* __restrict__ Xg = is_enc ? enc : h0;
  const unsigned short* __restrict__ Wc = is_enc ? W1c : W5c;
  const float* __restrict__ Vg = is_enc ? W4 : W8;
  const int row0 = is_enc ? wg * 128 : wg * 128 - M_ENC;

  // LDS: [A0 16K][B0 32K][A1 16K][B1 32K][lred 4K] = 100 KB
  __shared__ char lds_raw[2 * 49152 + 4096];
  float* lred = (float*)(lds_raw + 2 * 49152);   // [8][128]

  float vvv[4];
#pragma unroll
  for (int cf = 0; cf < 4; ++cf) vvv[cf] = Vg[colg * 64 + cf * 16 + l15];

  f4 acc[4][4];
#pragma unroll
  for (int i = 0; i < 4; ++i)
#pragma unroll
    for (int j = 0; j < 4; ++j) acc[i][j] = (f4){0.f, 0.f, 0.f, 0.f};

  // stage one K-step (32 k) into buffer `buf`: A = 1024 chunks (1/thread),
  // B = 2048 chunks (2/thread), all 16B global_load_lds.
#define STAGE(buf, kb_) do {                                                  \
    const int kbase_ = (kb_) * 32;                                            \
    const int arow_ = tid >> 3;                                               \
    const int sl_ = tid & 7;                                                  \
    const int sg_ = sl_ ^ (arow_ & 7);                                        \
    const float* gA_ = Xg + (size_t)(row0 + arow_) * HH + kbase_ + sg_ * 4;   \
    char* lA_ = lds_raw + (buf) * 49152 + tid * 16;                           \
    __builtin_amdgcn_global_load_lds(                                         \
        (const __attribute__((address_space(1))) void*)gA_,                   \
        (__attribute__((address_space(3))) void*)lA_, 16, 0, 0);              \
    _Pragma("unroll")                                                         \
    for (int p_ = 0; p_ < 2; ++p_) {                                          \
      const int idx_ = p_ * 1024 + tid;                                       \
      const char* gB_ = (const char*)Wc + (size_t)(kb_) * 32768 + idx_ * 16;  \
      char* lB_ = lds_raw + (buf) * 49152 + 16384 + idx_ * 16;                \
      __builtin_amdgcn_global_load_lds(                                       \
          (const __attribute__((address_space(1))) void*)gB_,                 \
          (__attribute__((address_space(3))) void*)lB_, 16, 0, 0);            \
    }                                                                         \
  } while (0)

  STAGE(0, 0);
  __syncthreads();

  int cur = 0;
#pragma unroll 1
  for (int kb = 0; kb < 32; ++kb) {
    if (kb < 31) STAGE(cur ^ 1, kb + 1);

    const char* Ab = lds_raw + cur * 49152;
    const char* Bb = Ab + 16384;

    short8 bfr[4];
#pragma unroll
    for (int cf = 0; cf < 4; ++cf)
      bfr[cf] = *(const short8*)(Bb + (((colg * 4 + cf) * 64 + lane) * 16));

#pragma unroll
    for (int rt = 0; rt < 4; ++rt) {
      const int row = rowg * 64 + rt * 16 + l15;
      const int x = row & 7;
      f4 a0 = *(const f4*)(Ab + row * 128 + (((lg * 2)     ^ x) * 16));
      f4 a1 = *(const f4*)(Ab + row * 128 + (((lg * 2 + 1) ^ x) * 16));
      short8 af;
      af[0] = f2b(a0[0]); af[1] = f2b(a0[1]); af[2] = f2b(a0[2]); af[3] = f2b(a0[3]);
      af[4] = f2b(a1[0]); af[5] = f2b(a1[1]); af[6] = f2b(a1[2]); af[7] = f2b(a1[3]);
#pragma unroll
      for (int cf = 0; cf < 4; ++cf)
        acc[rt][cf] = __builtin_amdgcn_mfma_f32_16x16x32_bf16(af, bfr[cf], acc[rt][cf], 0, 0, 0);
    }
    __syncthreads();
    cur ^= 1;
  }
#undef STAGE

  // epilogue: tanh, weight by V, reduce 16 lanes (cols), then across col-groups
#pragma unroll
  for (int rt = 0; rt < 4; ++rt) {
    float ps[4] = {0.f, 0.f, 0.f, 0.f};
#pragma unroll
    for (int cf = 0; cf < 4; ++cf) {
      const float w = vvv[cf];
#pragma unroll
      for (int r = 0; r < 4; ++r) ps[r] += w * tanh_fast(acc[rt][cf][r]);
    }
#pragma unroll
    for (int r = 0; r < 4; ++r) {
#pragma unroll
      for (int off = 1; off < 16; off <<= 1) ps[r] += __shfl_xor(ps[r], off);
    }
    if (l15 == 0) {
#pragma unroll
      for (int r = 0; r < 4; ++r)
        lred[colg * 128 + rowg * 64 + rt * 16 + lg * 4 + r] = ps[r];
    }
  }
  __syncthreads();
  if (tid < 128) {
    float s = 0.f;
#pragma unroll
    for (int c = 0; c < 8; ++c) s += lred[c * 128 + tid];
    e1[(size_t)wg * 128 + tid] = s;
  }
}

// ---------------- exi full logits: exf[b][s] = e1[s*B+b] + sum_a W4[2A+a]*tanh(ax[b,s]*W3[a]) ----
__global__ void exf_kernel(const float* __restrict__ e1, const float* __restrict__ ax,
                           const float* __restrict__ W3, const float* __restrict__ W4,
                           float* __restrict__ exf) {
  __shared__ float w3s[AA], w4r[AA];
  const int tid = threadIdx.x;  // 256
  for (int i = tid; i < AA; i += 256) { w3s[i] = W3[i]; w4r[i] = W4[2 * AA + i]; }
  __syncthreads();
  const int b = blockIdx.x >> 2;
  const int s = (blockIdx.x & 3) * 256 + tid;
  const float x = ax[b * SS + s];
  float er = 0.f;
#pragma unroll 8
  for (int a = 0; a < AA; ++a) er += w4r[a] * tanh_fast(x * w3s[a]);
  exf[b * SS + s] = e1[s * BB + b] + er;
}

// ---------------- softmax over s (contiguous rows) + ax_new output ----------------
__global__ void softmax_bs(const float* __restrict__ ein, const float* __restrict__ ax,
                           float* __restrict__ wout, float* __restrict__ axnew) {
  const int b = blockIdx.x, tid = threadIdx.x;  // 256 threads, 1024 elems
  __shared__ float red[256];
  float loc[4];
  float m = -1e30f;
#pragma unroll
  for (int i = 0; i < 4; ++i) { loc[i] = ein[b * SS + i * 256 + tid]; m = fmaxf(m, loc[i]); }
  red[tid] = m; __syncthreads();
  for (int off = 128; off > 0; off >>= 1) {
    if (tid < off) red[tid] = fmaxf(red[tid], red[tid + off]);
    __syncthreads();
  }
  m = red[0]; __syncthreads();
  float sum = 0.f;
#pragma unroll
  for (int i = 0; i < 4; ++i) { loc[i] = __expf(loc[i] - m); sum += loc[i]; }
  red[tid] = sum; __syncthreads();
  for (int off = 128; off > 0; off >>= 1) {
    if (tid < off) red[tid] += red[tid + off];
    __syncthreads();
  }
  const float inv = 1.f / red[0];
#pragma unroll
  for (int i = 0; i < 4; ++i) {
    const int s = i * 256 + tid;
    const float a_ = loc[i] * inv;
    wout[b * SS + s] = a_;
    axnew[b * SS + s] = ax[b * SS + s] + a_;
  }
}

// ---------------- softmax over t, input layout [t][b] strided ----------------
__global__ void softmax_tb(const float* __restrict__ ein, float* __restrict__ wout) {
  const int b = blockIdx.x, tid = threadIdx.x;
  __shared__ float red[256];
  float loc[4];
  float m = -1e30f;
#pragma unroll
  for (int i = 0; i < 4; ++i) { loc[i] = ein[(i * 256 + tid) * BB + b]; m = fmaxf(m, loc[i]); }
  red[tid] = m; __syncthreads();
  for (int off = 128; off > 0; off >>= 1) {
    if (tid < off) red[tid] = fmaxf(red[tid], red[tid + off]);
    __syncthreads();
  }
  m = red[0]; __syncthreads();
  float sum = 0.f;
#pragma unroll
  for (int i = 0; i < 4; ++i) { loc[i] = __expf(loc[i] - m); sum += loc[i]; }
  red[tid] = sum; __syncthreads();
  for (int off = 128; off > 0; off >>= 1) {
    if (tid < off) red[tid] += red[tid + off];
    __syncthreads();
  }
  const float inv = 1.f / red[0];
#pragma unroll
  for (int i = 0; i < 4; ++i) wout[b * TN + (i * 256 + tid)] = loc[i] * inv;
}

// ---------------- chunked weighted sum: part[b][ch][h] = sum_{s in ch} w[b,s]*X[s,b,h] ------------
__global__ void wpart(const float* __restrict__ X, const float* __restrict__ w,
                      float* __restrict__ part) {
  const int b = blockIdx.x / NCH, ch = blockIdx.x % NCH;
  const int tid = threadIdx.x;  // 256, each handles 4 h
  __shared__ float ws[SS / NCH];
  if (tid < SS / NCH) ws[tid] = w[b * SS + ch * (SS / NCH) + tid];
  __syncthreads();
  f4 acc = (f4){0.f, 0.f, 0.f, 0.f};
  const float* base = X + ((size_t)(ch * (SS / NCH)) * BB + b) * HH + tid * 4;
  for (int i = 0; i < SS / NCH; ++i) {
    f4 x = *(const f4*)(base + (size_t)i * BB * HH);
    acc += ws[i] * x;
  }
  *(f4*)&part[((size_t)(b * NCH + ch)) * HH + tid * 4] = acc;
}

__global__ void wreduce(const float* __restrict__ part, float* __restrict__ out) {
  const int idx = blockIdx.x * 256 + threadIdx.x;  // over B*H
  const int b = idx / HH, h = idx % HH;
  float s = 0.f;
#pragma unroll
  for (int ch = 0; ch < NCH; ++ch) s += part[((size_t)(b * NCH + ch)) * HH + h];
  out[idx] = s;
}

// ---------------- zi[b] = sigmoid( cxi[b,:].W11[0:H] + cti[b,:].W11[H:2H] ) ----------------
__global__ void zi_kernel(const float* __restrict__ cxi, const float* __restrict__ cti,
                          const float* __restrict__ W11, float* __restrict__ zi) {
  const int b = blockIdx.x, tid = threadIdx.x;  // 256
  float s = 0.f;
  for (int i = tid; i < HH; i += 256) s += cxi[b * HH + i] * W11[i] + cti[b * HH + i] * W11[HH + i];
  __shared__ float red[4];
  for (int off = 32; off > 0; off >>= 1) s += __shfl_down(s, off);
  if ((tid & 63) == 0) red[tid >> 6] = s;
  __syncthreads();
  if (tid == 0) {
    float t = red[0] + red[1] + red[2] + red[3];
    zi[b] = 1.f / (1.f + __expf(-t));
  }
}

// ---------------- ci[b,h] = z*tanh(cxi.W9[h,:]) + (1-z)*tanh(cti.W10[h,:]) ----------------
__global__ void ci_kernel(const float* __restrict__ cxi, const float* __restrict__ cti,
                          const float* __restrict__ W9, const float* __restrict__ W10,
                          const float* __restrict__ zi, float* __restrict__ out_ci) {
  const int b = blockIdx.x >> 2, hb = blockIdx.x & 3, tid = threadIdx.x;
  const int h = hb * 256 + tid;
  __shared__ float cx[HH], ct[HH];
  for (int i = tid; i < HH; i += 256) { cx[i] = cxi[b * HH + i]; ct[i] = cti[b * HH + i]; }
  __syncthreads();
  const float* __restrict__ w9r  = W9  + (size_t)h * HH;
  const float* __restrict__ w10r = W10 + (size_t)h * HH;
  float gx = 0.f, gt = 0.f;
  for (int k = 0; k < HH; k += 4) {
    f4 a = *(const f4*)(w9r + k);
    f4 c = *(const f4*)(w10r + k);
    gx += cx[k] * a[0] + cx[k + 1] * a[1] + cx[k + 2] * a[2] + cx[k + 3] * a[3];
    gt += ct[k] * c[0] + ct[k + 1] * c[1] + ct[k + 2] * c[2] + ct[k + 3] * c[3];
  }
  const float z = zi[b];
  out_ci[b * HH + h] = z * tanhf(gx) + (1.f - z) * tanhf(gt);
}

extern "C" void kernel_launch(void* const* d_in, const int* in_sizes, int n_in,
                              void* d_out, int out_size, void* d_ws, size_t ws_size,
                              hipStream_t stream) {
  const float* enc = (const float*)d_in[1];
  const float* h0  = (const float*)d_in[2];
  const float* ax  = (const float*)d_in[3];
  const float* W1  = (const float*)d_in[4];
  const float* W3  = (const float*)d_in[6];
  const float* W4  = (const float*)d_in[7];
  const float* W5  = (const float*)d_in[8];
  const float* W8  = (const float*)d_in[11];
  const float* W9  = (const float*)d_in[12];
  const float* W10 = (const float*)d_in[13];
  const float* W11 = (const float*)d_in[14];
  float* out = (float*)d_out;  // [0:B*H) ci, [B*H : 2*B*H) ax_new

  // Workspace layout (floats). W1c/W5c each 512*1024 bf16 = 262144 floats (1MB).
  // partx/partt ALIAS the Wc regions: Wc dead after e1_gemm; wprep recreates
  // Wc at the start of every call (deterministic across graph replays).
  float* w = (float*)d_ws;
  unsigned short* W1c = (unsigned short*)w;            // floats [0, 262144)
  unsigned short* W5c = (unsigned short*)(w + 262144); // floats [262144, 524288)
  float* partx = w;                  // aliases W1c
  float* partt = w + 262144;         // aliases W5c
  float* e1    = w + 524288;         // 65536
  float* exf   = w + 589824;         // 32768
  float* axi   = w + 622592;         // 32768
  float* ati   = w + 655360;         // 32768
  float* cxi   = w + 688128;         // 32768
  float* cti   = w + 720896;         // 32768
  float* zi    = w + 753664;         // 64    (end: ~3.01 MB)

  wprep<<<256, 256, 0, stream>>>(W1, W1c);
  wprep<<<256, 256, 0, stream>>>(W5, W5c);
  e1_gemm<<<M_TOT / 128, 1024, 0, stream>>>(enc, h0, W1c, W5c, W4, W8, e1);
  exf_kernel<<<BB * 4, 256, 0, stream>>>(e1, ax, W3, W4, exf);
  softmax_bs<<<BB, 256, 0, stream>>>(exf, ax, axi, out + BB * HH);
  softmax_tb<<<BB, 256, 0, stream>>>(e1 + M_ENC, ati);
  wpart<<<BB * NCH, 256, 0, stream>>>(enc, axi, partx);
  wpart<<<BB * NCH, 256, 0, stream>>>(h0, ati, partt);
  wreduce<<<BB * HH / 256, 256, 0, stream>>>(partx, cxi);
  wreduce<<<BB * HH / 256, 256, 0, stream>>>(partt, cti);
  zi_kernel<<<BB, 256, 0, stream>>>(cxi, cti, W11, zi);
  ci_kernel<<<BB * 4, 256, 0, stream>>>(cxi, cti, W9, W10, zi, out);
}

// Round 6
// 242.320 us; speedup vs baseline: 2.6444x; 1.0581x over previous
//
#include <hip/hip_runtime.h>
#include <hip/hip_bf16.h>

#define HH 1024
#define AA 512
#define BB 32
#define SS 1024
#define TN 1024
#define M_ENC (SS*BB)
#define M_TOT ((SS+TN)*BB)
#define NCH 8

typedef __attribute__((ext_vector_type(8))) short short8;
typedef __attribute__((ext_vector_type(4))) float f4;

union bfu { __hip_bfloat16 h; unsigned short u; };
__device__ __forceinline__ unsigned short f2b(float x) {
  bfu t; t.h = __float2bfloat16(x); return t.u;
}
__device__ __forceinline__ float tanh_fast(float x) {
  float e = __expf(2.f * x);
  return 1.f - 2.f / (e + 1.f);
}

// ---- one-time W -> bf16 fragment-order repack ------------------------------
// Wc layout: frag id t = ((kb*32 + rg)*64 + lane), 8 bf16 per frag.
// fragment holds W[rg*16 + (lane&15)][kb*32 + (lane>>4)*8 + j]
__global__ void wprep(const float* __restrict__ W, unsigned short* __restrict__ Wc) {
  const int t = blockIdx.x * 256 + threadIdx.x;     // 0..65535
  const int lane = t & 63;
  const int rg = (t >> 6) & 31;
  const int kb = t >> 11;
  const int row = rg * 16 + (lane & 15);
  const int k = kb * 32 + ((lane >> 4) << 3);
  const float* src = W + (size_t)row * HH + k;
  f4 v0 = *(const f4*)(src);
  f4 v1 = *(const f4*)(src + 4);
  short8 o;
  o[0] = f2b(v0[0]); o[1] = f2b(v0[1]); o[2] = f2b(v0[2]); o[3] = f2b(v0[3]);
  o[4] = f2b(v1[0]); o[5] = f2b(v1[1]); o[6] = f2b(v1[2]); o[7] = f2b(v1[3]);
  *(short8*)(Wc + (size_t)t * 8) = o;
}

// ---- big fused GEMM: e1[row] = sum_a V[a]*tanh( X[row,:] . W[a,:] ) --------
// BM=128, 1024 threads = 16 waves as 2(row)x8(col); wave tile 64x64, acc[4][4].
// A: register-staged fp32 -> bf16 -> ds_write (XOR-swizzled, 2-way free);
// frag = ONE ds_read_b128. B: fragment-ordered bf16 via global_load_lds
// (linear). Double-buffered 2x(8K+32K)=80KB; lred aliases buf0.A.
// Per iter: issue A-reg loads + B gll for k+1, compute k, cvt+ds_write A(k+1),
// one __syncthreads (T14 async split; prefetch in flight across compute).
__global__ __launch_bounds__(1024, 4)
void e1_gemm(const float* __restrict__ enc, const float* __restrict__ h0,
             const unsigned short* __restrict__ W1c, const unsigned short* __restrict__ W5c,
             const float* __restrict__ W4, const float* __restrict__ W8,
             float* __restrict__ e1) {
  const int wg   = blockIdx.x;        // 512 blocks, 128 rows each
  const int tid  = threadIdx.x;       // 1024
  const int lane = tid & 63;
  const int wave = tid >> 6;          // 0..15
  const int rowg = wave >> 3;         // 0..1  (64-row group)
  const int colg = wave & 7;          // 0..7  (64-col group)
  const int l15  = lane & 15;
  const int lg   = lane >> 4;         // 0..3

  const bool is_enc = (wg * 128) < M_ENC;
  const float* __restrict__ Xg = is_enc ? enc : h0;
  const unsigned short* __restrict__ Wc = is_enc ? W1c : W5c;
  const float* __restrict__ Vg = is_enc ? W4 : W8;
  const int row0 = is_enc ? wg * 128 : wg * 128 - M_ENC;

  // LDS: buf0 [A 8K][B 32K] buf1 [A 8K][B 32K] = 80 KB; lred aliases buf0.A
  __shared__ char lds_raw[2 * 40960];
  float* lred = (float*)lds_raw;      // [8][128], used only in epilogue

  float vvv[4];
#pragma unroll
  for (int cf = 0; cf < 4; ++cf) vvv[cf] = Vg[colg * 64 + cf * 16 + l15];

  f4 acc[4][4];
#pragma unroll
  for (int i = 0; i < 4; ++i)
#pragma unroll
    for (int j = 0; j < 4; ++j) acc[i][j] = (f4){0.f, 0.f, 0.f, 0.f};

  // ---- A staging geometry (threads < 512): thread -> (row, kslot) ----------
  const int arow  = tid >> 2;                    // 0..127 (tid<512)
  const int kslot = tid & 3;                     // 0..3 (8 bf16 each)
  const int acol  = kslot ^ ((arow >> 1) & 3);   // XOR swizzle
  const float* aSrc = Xg + (size_t)(row0 + arow) * HH + kslot * 8;
  const int aDst = arow * 64 + acol * 16;        // byte offset in A region

  // ---- fragment read bases --------------------------------------------------
  // A frag: row = rowg*64 + rt*16 + l15, kslot = lg; swizzle term lane-const.
  const int aRd = (rowg * 64 + l15) * 64 + ((lg ^ ((l15 >> 1) & 3)) << 4);
  // B frag: chunk (colg*4+cf)*64 + lane, 16B each.
  const int bRd = colg * 4096 + lane * 16;

#define BGLL(buf, kb_) do {                                                   \
    _Pragma("unroll")                                                         \
    for (int p_ = 0; p_ < 2; ++p_) {                                          \
      const int idx_ = p_ * 1024 + tid;                                       \
      const char* gB_ = (const char*)Wc + (size_t)(kb_) * 32768 + idx_ * 16;  \
      char* lB_ = lds_raw + (buf) * 40960 + 8192 + idx_ * 16;                 \
      __builtin_amdgcn_global_load_lds(                                       \
          (const __attribute__((address_space(1))) void*)gB_,                 \
          (__attribute__((address_space(3))) void*)lB_, 16, 0, 0);            \
    }                                                                         \
  } while (0)

#define AWRITE(buf, v0_, v1_) do {                                            \
    short8 o_;                                                                \
    o_[0] = f2b(v0_[0]); o_[1] = f2b(v0_[1]);                                 \
    o_[2] = f2b(v0_[2]); o_[3] = f2b(v0_[3]);                                 \
    o_[4] = f2b(v1_[0]); o_[5] = f2b(v1_[1]);                                 \
    o_[6] = f2b(v1_[2]); o_[7] = f2b(v1_[3]);                                 \
    *(short8*)(lds_raw + (buf) * 40960 + aDst) = o_;                          \
  } while (0)

  // ---- prologue: stage kb=0 --------------------------------------------------
  f4 a0n, a1n;
  if (tid < 512) { a0n = *(const f4*)(aSrc); a1n = *(const f4*)(aSrc + 4); }
  BGLL(0, 0);
  if (tid < 512) AWRITE(0, a0n, a1n);
  __syncthreads();

  int cur = 0;
#pragma unroll 1
  for (int kb = 0; kb < 32; ++kb) {
    // issue next-step loads first (overlap with compute)
    if (kb < 31) {
      if (tid < 512) {
        a0n = *(const f4*)(aSrc + (kb + 1) * 32);
        a1n = *(const f4*)(aSrc + (kb + 1) * 32 + 4);
      }
      BGLL(cur ^ 1, kb + 1);
    }

    const char* Ab = lds_raw + cur * 40960;
    const char* Bb = Ab + 8192;

    short8 bfr[4];
#pragma unroll
    for (int cf = 0; cf < 4; ++cf)
      bfr[cf] = *(const short8*)(Bb + bRd + cf * 1024);

#pragma unroll
    for (int rt = 0; rt < 4; ++rt) {
      short8 af = *(const short8*)(Ab + aRd + rt * 1024);
#pragma unroll
      for (int cf = 0; cf < 4; ++cf)
        acc[rt][cf] = __builtin_amdgcn_mfma_f32_16x16x32_bf16(af, bfr[cf], acc[rt][cf], 0, 0, 0);
    }

    // late half of the async stage: cvt + LDS write (vmcnt wait auto on a0n/a1n)
    if (kb < 31 && tid < 512) AWRITE(cur ^ 1, a0n, a1n);
    __syncthreads();
    cur ^= 1;
  }
#undef BGLL
#undef AWRITE

  // epilogue: tanh, weight by V, reduce 16 lanes (cols), then across col-groups
#pragma unroll
  for (int rt = 0; rt < 4; ++rt) {
    float ps[4] = {0.f, 0.f, 0.f, 0.f};
#pragma unroll
    for (int cf = 0; cf < 4; ++cf) {
      const float w = vvv[cf];
#pragma unroll
      for (int r = 0; r < 4; ++r) ps[r] += w * tanh_fast(acc[rt][cf][r]);
    }
#pragma unroll
    for (int r = 0; r < 4; ++r) {
#pragma unroll
      for (int off = 1; off < 16; off <<= 1) ps[r] += __shfl_xor(ps[r], off);
    }
    if (l15 == 0) {
#pragma unroll
      for (int r = 0; r < 4; ++r)
        lred[colg * 128 + rowg * 64 + rt * 16 + lg * 4 + r] = ps[r];
    }
  }
  __syncthreads();
  if (tid < 128) {
    float s = 0.f;
#pragma unroll
    for (int c = 0; c < 8; ++c) s += lred[c * 128 + tid];
    e1[(size_t)wg * 128 + tid] = s;
  }
}

// ---------------- exi full logits: exf[b][s] = e1[s*B+b] + sum_a W4[2A+a]*tanh(ax[b,s]*W3[a]) ----
__global__ void exf_kernel(const float* __restrict__ e1, const float* __restrict__ ax,
                           const float* __restrict__ W3, const float* __restrict__ W4,
                           float* __restrict__ exf) {
  __shared__ float w3s[AA], w4r[AA];
  const int tid = threadIdx.x;  // 256
  for (int i = tid; i < AA; i += 256) { w3s[i] = W3[i]; w4r[i] = W4[2 * AA + i]; }
  __syncthreads();
  const int b = blockIdx.x >> 2;
  const int s = (blockIdx.x & 3) * 256 + tid;
  const float x = ax[b * SS + s];
  float er = 0.f;
#pragma unroll 8
  for (int a = 0; a < AA; ++a) er += w4r[a] * tanh_fast(x * w3s[a]);
  exf[b * SS + s] = e1[s * BB + b] + er;
}

// ---------------- softmax over s (contiguous rows) + ax_new output ----------------
__global__ void softmax_bs(const float* __restrict__ ein, const float* __restrict__ ax,
                           float* __restrict__ wout, float* __restrict__ axnew) {
  const int b = blockIdx.x, tid = threadIdx.x;  // 256 threads, 1024 elems
  __shared__ float red[256];
  float loc[4];
  float m = -1e30f;
#pragma unroll
  for (int i = 0; i < 4; ++i) { loc[i] = ein[b * SS + i * 256 + tid]; m = fmaxf(m, loc[i]); }
  red[tid] = m; __syncthreads();
  for (int off = 128; off > 0; off >>= 1) {
    if (tid < off) red[tid] = fmaxf(red[tid], red[tid + off]);
    __syncthreads();
  }
  m = red[0]; __syncthreads();
  float sum = 0.f;
#pragma unroll
  for (int i = 0; i < 4; ++i) { loc[i] = __expf(loc[i] - m); sum += loc[i]; }
  red[tid] = sum; __syncthreads();
  for (int off = 128; off > 0; off >>= 1) {
    if (tid < off) red[tid] += red[tid + off];
    __syncthreads();
  }
  const float inv = 1.f / red[0];
#pragma unroll
  for (int i = 0; i < 4; ++i) {
    const int s = i * 256 + tid;
    const float a_ = loc[i] * inv;
    wout[b * SS + s] = a_;
    axnew[b * SS + s] = ax[b * SS + s] + a_;
  }
}

// ---------------- softmax over t, input layout [t][b] strided ----------------
__global__ void softmax_tb(const float* __restrict__ ein, float* __restrict__ wout) {
  const int b = blockIdx.x, tid = threadIdx.x;
  __shared__ float red[256];
  float loc[4];
  float m = -1e30f;
#pragma unroll
  for (int i = 0; i < 4; ++i) { loc[i] = ein[(i * 256 + tid) * BB + b]; m = fmaxf(m, loc[i]); }
  red[tid] = m; __syncthreads();
  for (int off = 128; off > 0; off >>= 1) {
    if (tid < off) red[tid] = fmaxf(red[tid], red[tid + off]);
    __syncthreads();
  }
  m = red[0]; __syncthreads();
  float sum = 0.f;
#pragma unroll
  for (int i = 0; i < 4; ++i) { loc[i] = __expf(loc[i] - m); sum += loc[i]; }
  red[tid] = sum; __syncthreads();
  for (int off = 128; off > 0; off >>= 1) {
    if (tid < off) red[tid] += red[tid + off];
    __syncthreads();
  }
  const float inv = 1.f / red[0];
#pragma unroll
  for (int i = 0; i < 4; ++i) wout[b * TN + (i * 256 + tid)] = loc[i] * inv;
}

// ---------------- chunked weighted sum: part[b][ch][h] = sum_{s in ch} w[b,s]*X[s,b,h] ------------
__global__ void wpart(const float* __restrict__ X, const float* __restrict__ w,
                      float* __restrict__ part) {
  const int b = blockIdx.x / NCH, ch = blockIdx.x % NCH;
  const int tid = threadIdx.x;  // 256, each handles 4 h
  __shared__ float ws[SS / NCH];
  if (tid < SS / NCH) ws[tid] = w[b * SS + ch * (SS / NCH) + tid];
  __syncthreads();
  f4 acc = (f4){0.f, 0.f, 0.f, 0.f};
  const float* base = X + ((size_t)(ch * (SS / NCH)) * BB + b) * HH + tid * 4;
#pragma unroll 4
  for (int i = 0; i < SS / NCH; ++i) {
    f4 x = *(const f4*)(base + (size_t)i * BB * HH);
    acc += ws[i] * x;
  }
  *(f4*)&part[((size_t)(b * NCH + ch)) * HH + tid * 4] = acc;
}

__global__ void wreduce(const float* __restrict__ part, float* __restrict__ out) {
  const int idx = blockIdx.x * 256 + threadIdx.x;  // over B*H
  const int b = idx / HH, h = idx % HH;
  float s = 0.f;
#pragma unroll
  for (int ch = 0; ch < NCH; ++ch) s += part[((size_t)(b * NCH + ch)) * HH + h];
  out[idx] = s;
}

// ---------------- zi[b] = sigmoid( cxi[b,:].W11[0:H] + cti[b,:].W11[H:2H] ) ----------------
__global__ void zi_kernel(const float* __restrict__ cxi, const float* __restrict__ cti,
                          const float* __restrict__ W11, float* __restrict__ zi) {
  const int b = blockIdx.x, tid = threadIdx.x;  // 256
  float s = 0.f;
  for (int i = tid; i < HH; i += 256) s += cxi[b * HH + i] * W11[i] + cti[b * HH + i] * W11[HH + i];
  __shared__ float red[4];
  for (int off = 32; off > 0; off >>= 1) s += __shfl_down(s, off);
  if ((tid & 63) == 0) red[tid >> 6] = s;
  __syncthreads();
  if (tid == 0) {
    float t = red[0] + red[1] + red[2] + red[3];
    zi[b] = 1.f / (1.f + __expf(-t));
  }
}

// ---------------- ci[b,h] = z*tanh(cxi.W9[h,:]) + (1-z)*tanh(cti.W10[h,:]) ----------------
__global__ void ci_kernel(const float* __restrict__ cxi, const float* __restrict__ cti,
                          const float* __restrict__ W9, const float* __restrict__ W10,
                          const float* __restrict__ zi, float* __restrict__ out_ci) {
  const int b = blockIdx.x >> 2, hb = blockIdx.x & 3, tid = threadIdx.x;
  const int h = hb * 256 + tid;
  __shared__ float cx[HH], ct[HH];
  for (int i = tid; i < HH; i += 256) { cx[i] = cxi[b * HH + i]; ct[i] = cti[b * HH + i]; }
  __syncthreads();
  const float* __restrict__ w9r  = W9  + (size_t)h * HH;
  const float* __restrict__ w10r = W10 + (size_t)h * HH;
  float gx = 0.f, gt = 0.f;
  for (int k = 0; k < HH; k += 4) {
    f4 a = *(const f4*)(w9r + k);
    f4 c = *(const f4*)(w10r + k);
    gx += cx[k] * a[0] + cx[k + 1] * a[1] + cx[k + 2] * a[2] + cx[k + 3] * a[3];
    gt += ct[k] * c[0] + ct[k + 1] * c[1] + ct[k + 2] * c[2] + ct[k + 3] * c[3];
  }
  const float z = zi[b];
  out_ci[b * HH + h] = z * tanhf(gx) + (1.f - z) * tanhf(gt);
}

extern "C" void kernel_launch(void* const* d_in, const int* in_sizes, int n_in,
                              void* d_out, int out_size, void* d_ws, size_t ws_size,
                              hipStream_t stream) {
  const float* enc = (const float*)d_in[1];
  const float* h0  = (const float*)d_in[2];
  const float* ax  = (const float*)d_in[3];
  const float* W1  = (const float*)d_in[4];
  const float* W3  = (const float*)d_in[6];
  const float* W4  = (const float*)d_in[7];
  const float* W5  = (const float*)d_in[8];
  const float* W8  = (const float*)d_in[11];
  const float* W9  = (const float*)d_in[12];
  const float* W10 = (const float*)d_in[13];
  const float* W11 = (const float*)d_in[14];
  float* out = (float*)d_out;  // [0:B*H) ci, [B*H : 2*B*H) ax_new

  // Workspace layout (floats). W1c/W5c each 512*1024 bf16 = 262144 floats (1MB).
  // partx/partt ALIAS the Wc regions: Wc dead after e1_gemm; wprep recreates
  // Wc at the start of every call (deterministic across graph replays).
  float* w = (float*)d_ws;
  unsigned short* W1c = (unsigned short*)w;            // floats [0, 262144)
  unsigned short* W5c = (unsigned short*)(w + 262144); // floats [262144, 524288)
  float* partx = w;                  // aliases W1c
  float* partt = w + 262144;         // aliases W5c
  float* e1    = w + 524288;         // 65536
  float* exf   = w + 589824;         // 32768
  float* axi   = w + 622592;         // 32768
  float* ati   = w + 655360;         // 32768
  float* cxi   = w + 688128;         // 32768
  float* cti   = w + 720896;         // 32768
  float* zi    = w + 753664;         // 64    (end: ~3.01 MB)

  wprep<<<256, 256, 0, stream>>>(W1, W1c);
  wprep<<<256, 256, 0, stream>>>(W5, W5c);
  e1_gemm<<<M_TOT / 128, 1024, 0, stream>>>(enc, h0, W1c, W5c, W4, W8, e1);
  exf_kernel<<<BB * 4, 256, 0, stream>>>(e1, ax, W3, W4, exf);
  softmax_bs<<<BB, 256, 0, stream>>>(exf, ax, axi, out + BB * HH);
  softmax_tb<<<BB, 256, 0, stream>>>(e1 + M_ENC, ati);
  wpart<<<BB * NCH, 256, 0, stream>>>(enc, axi, partx);
  wpart<<<BB * NCH, 256, 0, stream>>>(h0, ati, partt);
  wreduce<<<BB * HH / 256, 256, 0, stream>>>(partx, cxi);
  wreduce<<<BB * HH / 256, 256, 0, stream>>>(partt, cti);
  zi_kernel<<<BB, 256, 0, stream>>>(cxi, cti, W11, zi);
  ci_kernel<<<BB * 4, 256, 0, stream>>>(cxi, cti, W9, W10, zi, out);
}